// Round 6
// baseline (296.748 us; speedup 1.0000x reference)
//
#include <hip/hip_runtime.h>
#include <math.h>

// MemoryBuffer: B=32, KD=VD=512, M=2048.
// Shift-matrix matmul eliminated algebraically:
//   scores[b,0] = dot(key_in[b], x[b]); scores[b,m] = dot(key_mem[b,:,m-1], x[b])
//   out[b,v]    = w0*value_in[b,v] + dot(value_mem[b,v,:], wl[b,:])
//   with wl[c] = softmax_w[c+1], wl[M-1] = 0  (aligned full-row dot).
// Kernel-side floor: 256 MiB streamed @ ~6.5 TB/s ~= 40 us; harness adds
// ~215 us fixed (512 MiB ws re-poison fill + 248 MB d_in restore).
// R6: drop NT loads (untested delta, possible read-burst penalty);
//     k_scores FPC 32->16 (VGPR pressure); k_out direct-L1 wl (no LDS/barrier).

#define B_   32
#define KD_  512
#define VD_  512
#define M_   2048
#define FCH  32           // f-chunks in k_scores
#define FPC  (KD_ / FCH)  // 16 rows per chunk
#define MCH  2            // 2 column-chunks of 1024

typedef float f4 __attribute__((ext_vector_type(4)));

// ------------------------------------------------------------------
// Kernel 1: partial[fc][b][c] = dot over FPC f-rows. Grid (MCH*FCH, B) = 2048
// blocks -> ~5 blocks/CU. 16 independent f4 loads in flight per thread.
__global__ __launch_bounds__(256) void k_scores(
    const float* __restrict__ key_mem,
    const float* __restrict__ x,
    float* __restrict__ partial)
{
    const int b   = blockIdx.y;
    const int mc  = blockIdx.x & (MCH - 1);
    const int fc  = blockIdx.x >> 1;
    const int tid = threadIdx.x;

    __shared__ float xs[FPC];
    if (tid < FPC) xs[tid] = x[b * KD_ + fc * FPC + tid];
    __syncthreads();

    const int c0 = mc * 1024 + tid * 4;   // covers 0..2047 across mc=0,1
    const float* kp = key_mem + ((size_t)(b * KD_ + fc * FPC)) * M_ + c0;

    f4 acc = {0.f, 0.f, 0.f, 0.f};
    #pragma unroll
    for (int f = 0; f < FPC; ++f) {
        const f4 kk = *(const f4*)(kp + (size_t)f * M_);
        acc += kk * xs[f];
    }
    *(f4*)(partial + ((size_t)fc * B_ + b) * M_ + c0) = acc;
}

// ------------------------------------------------------------------
// Kernel 2: per-b softmax, 1024 threads, 2 m's/thread, FCH independent
// partial loads each (pure ILP). Writes shifted weights wl + w0.
__global__ __launch_bounds__(1024) void k_softmax(
    const float* __restrict__ partial,
    const float* __restrict__ x,
    const float* __restrict__ key_in,
    float* __restrict__ wl,
    float* __restrict__ w0)
{
    const int b    = blockIdx.x;
    const int tid  = threadIdx.x;
    const int wave = tid >> 6, lane = tid & 63;
    __shared__ float red[16];

    // sdot = dot(key_in[b], x[b])  (KD=512 < 1024 threads)
    float p = (tid < KD_) ? key_in[b * KD_ + tid] * x[b * KD_ + tid] : 0.f;
    for (int off = 32; off; off >>= 1) p += __shfl_down(p, off);
    if (lane == 0) red[wave] = p;
    __syncthreads();
    float sdot = 0.f;
    #pragma unroll
    for (int i = 0; i < 16; ++i) sdot += red[i];
    __syncthreads();

    // gather scores for m = tid, tid+1024
    float s[2];
    #pragma unroll
    for (int k = 0; k < 2; ++k) {
        const int m = tid + k * 1024;
        if (m == 0) s[k] = sdot;
        else {
            float a = 0.f;
            #pragma unroll
            for (int fcc = 0; fcc < FCH; ++fcc)
                a += partial[((size_t)fcc * B_ + b) * M_ + (m - 1)];
            s[k] = a;
        }
    }

    // block max
    float mx = fmaxf(s[0], s[1]);
    for (int off = 32; off; off >>= 1) mx = fmaxf(mx, __shfl_down(mx, off));
    if (lane == 0) red[wave] = mx;
    __syncthreads();
    mx = red[0];
    #pragma unroll
    for (int i = 1; i < 16; ++i) mx = fmaxf(mx, red[i]);
    __syncthreads();

    // exp + block sum
    float e0 = __expf(s[0] - mx), e1 = __expf(s[1] - mx);
    float sum = e0 + e1;
    for (int off = 32; off; off >>= 1) sum += __shfl_down(sum, off);
    if (lane == 0) red[wave] = sum;
    __syncthreads();
    sum = 0.f;
    #pragma unroll
    for (int i = 0; i < 16; ++i) sum += red[i];
    const float inv = 1.0f / sum;

    #pragma unroll
    for (int k = 0; k < 2; ++k) {
        const int m = tid + k * 1024;
        const float w = (k ? e1 : e0) * inv;
        if (m == 0) w0[b] = w;
        else wl[(size_t)b * M_ + (m - 1)] = w;
    }
    if (tid == 0) wl[(size_t)b * M_ + (M_ - 1)] = 0.f;
}

// ------------------------------------------------------------------
// Kernel 3: out[b,v] = w0[b]*value_in[b,v] + dot(value_mem[b,v,:], wl[b,:])
// Grid (VD/8, B) = 2048 blocks, 2 rows/wave. wl read direct from global:
// 8 KiB/b is L1-hot after the first row (64 blocks/b share it) -> no LDS,
// no barrier, loads flow freely.
__global__ __launch_bounds__(256) void k_out(
    const float* __restrict__ value_mem,
    const float* __restrict__ value_in,
    const float* __restrict__ wl,
    const float* __restrict__ w0,
    float* __restrict__ out)
{
    const int b   = blockIdx.y;
    const int vc  = blockIdx.x;
    const int tid = threadIdx.x;
    const int wave = tid >> 6, lane = tid & 63;

    const float* wp = wl + (size_t)b * M_;
    const float w0b = w0[b];

    #pragma unroll
    for (int r = 0; r < 2; ++r) {
        const int v = vc * 8 + wave * 2 + r;
        const float* vp = value_mem + ((size_t)(b * VD_ + v)) * M_;
        f4 acc = {0.f, 0.f, 0.f, 0.f};
        #pragma unroll
        for (int it = 0; it < 8; ++it) {
            const int idx = it * 256 + lane * 4;   // 64 lanes x 4 = 256/iter
            const f4 vv = *(const f4*)(vp + idx);
            const f4 ww = *(const f4*)(wp + idx);
            acc += vv * ww;
        }
        float a = acc[0] + acc[1] + acc[2] + acc[3];
        for (int off = 32; off; off >>= 1) a += __shfl_down(a, off);
        if (lane == 0) out[b * VD_ + v] = a + w0b * value_in[b * VD_ + v];
    }
}

// ------------------------------------------------------------------
extern "C" void kernel_launch(void* const* d_in, const int* in_sizes, int n_in,
                              void* d_out, int out_size, void* d_ws, size_t ws_size,
                              hipStream_t stream)
{
    const float* key_mem   = (const float*)d_in[0];
    const float* value_mem = (const float*)d_in[1];
    const float* x         = (const float*)d_in[2];
    const float* key_in    = (const float*)d_in[3];
    const float* value_in  = (const float*)d_in[4];
    // d_in[5] = II shift matrix: structure known, never read.

    float* out = (float*)d_out;

    // ws layout: partial (FCH*B*M = 8 MiB) | wl (B*M) | w0 (B)
    float* partial = (float*)d_ws;
    float* wl      = partial + (size_t)FCH * B_ * M_;
    float* w0      = wl + (size_t)B_ * M_;

    k_scores <<<dim3(MCH * FCH, B_), 256,  0, stream>>>(key_mem, x, partial);
    k_softmax<<<dim3(B_),            1024, 0, stream>>>(partial, x, key_in, wl, w0);
    k_out    <<<dim3(VD_ / 8, B_),   256,  0, stream>>>(value_mem, value_in, wl, w0, out);
}